// Round 8
// baseline (196.322 us; speedup 1.0000x reference)
//
#include <hip/hip_runtime.h>
#include <math.h>

// Problem constants (B,S,D,V,C) = (32, 2048, 512, 32000, 2)
#define BB   32
#define SS   2048
#define DD   512
#define VV   32000
#define JT   36              // 32 q-rows + w0 + w1 + 2 zero rows
#define QJS  17              // q LDS j-row stride, float4 (16 + 1 pad)
#define QRS  612             // q LDS region stride, float4 (36*17; 2448 fl ≡16 mod 32)
#define GCH  8               // gather token-chunks per batch

// ---------------------------------------------------------------------------
// Pass 0: QT[36][512] (j-major): row j<32 = emb[tokens[j,0]], 32/33 = cls_w,
// 34/35 = zero. One block per j-row, 128 threads x float4.
// ---------------------------------------------------------------------------
__global__ __launch_bounds__(128) void build_qt(
    const int* __restrict__ tokens, const float* __restrict__ emb,
    const float* __restrict__ cls_w, float* __restrict__ QT)
{
    const int j   = blockIdx.x;    // 0..35
    const int tid = threadIdx.x;   // 128 threads * float4 = 512 floats
    float4 v = make_float4(0.f, 0.f, 0.f, 0.f);
    if (j < 32) {
        const int tok = tokens[(size_t)j * SS];
        v = ((const float4*)(emb + (size_t)tok * DD))[tid];
    } else if (j < 34) {
        v = ((const float4*)(cls_w + (size_t)(j - 32) * DD))[tid];
    }
    ((float4*)QT)[j * (DD / 4) + tid] = v;
}

// ---------------------------------------------------------------------------
// Pass A: Sh[h][v][j] = sum_{d in half h} emb[v][d] * QT[j][d]
// K-split-2. Block = 64 rows x 256 dims; grid (500,2); 4 blocks/CU (39.2 KB).
// Lane = (g = l&3: 64-dim subseg, jg = (l>>2)&3: 9 j's, rg = l>>4: 4-row grp).
// Thread: 4 rows x 9 j x 64 dims; per 4-dim chunk 9 ds_read_b128 -> 144 FMA.
//
// r7 fixes, all by construction:
//  * BANKS (enumerated): q region g at f4 g*612, j-row stride 17 f4. Bank =
//    4*(4g + jg + jj + c) mod 32; (4g+jg) mod 8 covers each quad EXACTLY 2x
//    over the 16 (g,jg) pairs -> 2-way = free. (r7: 2.3M conflicts -> ~0)
//  * FETCH: per super-chunk a lane loads 4 consecutive f4 of one row =
//    exactly one 64B-aligned line, back-to-back -> MSHR merge, no L1-churn
//    refetch. (r7: 143 MB -> ~66 MB)
//  * WRITE: after g-butterfly, 36-shfl column-gather gives each jg==0 lane a
//    FULL row (144 B contiguous, 9 x dwordx4) — r4's measured-clean pattern.
//    (r7: 70 MB -> ~9.7 MB)
// ---------------------------------------------------------------------------
__global__ __launch_bounds__(256, 4) void score_pass(
    const float* __restrict__ emb, const float* __restrict__ QT,
    float* __restrict__ Sh)
{
    const int bx  = blockIdx.x;          // 0..499 row block
    const int h   = blockIdx.y;          // 0..1   K half
    const int tid = threadIdx.x;
    const int w   = tid >> 6;            // wave 0..3
    const int l   = tid & 63;
    const int g   = l & 3;               // 64-dim subsegment
    const int jg  = (l >> 2) & 3;        // j-group (9 j's)
    const int rg  = l >> 4;              // row group (4 rows)

    __shared__ float4 qs[4 * QRS];       // 39.2 KB -> 4 blocks/CU

    // ---- stage q: region g = QT[ j ][ h*256 + g*64 .. +64 ), J-major
    // 2304 f4 total = 9 x 256; dst f4 = g*612 + j*17 + c4 (padded rows)
#pragma unroll
    for (int it = 0; it < 9; ++it) {
        const int t  = it * 256 + tid;
        const int gg = t / 576, r = t % 576;
        const int j  = r >> 4,  c4 = r & 15;
        qs[gg * QRS + j * QJS + c4] =
            ((const float4*)QT)[j * 128 + h * 64 + gg * 16 + c4];
    }
    __syncthreads();

    const int row0 = bx * 64 + w * 16 + rg * 4;      // thread's 4 rows
    const float* xb = emb + (size_t)row0 * DD + h * 256 + g * 64;

    float acc[36];                                   // [rr][jj] = acc[rr*9+jj]
#pragma unroll
    for (int k = 0; k < 36; ++k) acc[k] = 0.f;

    for (int sc = 0; sc < 4; ++sc) {                 // 16-dim super-chunks
        // one FULL 64B line per row, 4 back-to-back f4 loads (MSHR-merged)
        float4 xv[4][4];
#pragma unroll
        for (int rr = 0; rr < 4; ++rr)
#pragma unroll
            for (int p = 0; p < 4; ++p)
                xv[rr][p] = *(const float4*)(xb + rr * DD + sc * 16 + p * 4);

#pragma unroll
        for (int u = 0; u < 4; ++u) {                // 4-dim sub-chunks
            const int c = sc * 4 + u;
            const float4* qrow = qs + g * QRS + (jg * 9) * QJS + c;
#pragma unroll
            for (int jj = 0; jj < 9; ++jj) {
                const float4 q = qrow[jj * QJS];     // b128, 2-way banked
#pragma unroll
                for (int rr = 0; rr < 4; ++rr) {
                    float a = acc[rr * 9 + jj];
                    a = fmaf(xv[rr][u].x, q.x, a);
                    a = fmaf(xv[rr][u].y, q.y, a);
                    a = fmaf(xv[rr][u].z, q.z, a);
                    a = fmaf(xv[rr][u].w, q.w, a);
                    acc[rr * 9 + jj] = a;
                }
            }
        }
    }

    // ---- in-wave K-reduction over the 4 g-lanes (lane bits 0..1)
#pragma unroll
    for (int off = 1; off < 4; off <<= 1)
#pragma unroll
        for (int k = 0; k < 36; ++k)
            acc[k] += __shfl_xor(acc[k], off);

    // ---- column-gather: lane (g,0,rg) collects row row0+g's full 36 cols.
    // Source lane (g, cb, rg) sends acc[rr = its own g][jj] (static selects).
    float out9[9];
#pragma unroll
    for (int jj = 0; jj < 9; ++jj) {
        float v = acc[jj];
        v = (g == 1) ? acc[9  + jj] : v;
        v = (g == 2) ? acc[18 + jj] : v;
        v = (g == 3) ? acc[27 + jj] : v;
        out9[jj] = v;
    }
    float out[36];
#pragma unroll
    for (int cb = 0; cb < 4; ++cb)
#pragma unroll
        for (int jj = 0; jj < 9; ++jj)
            out[cb * 9 + jj] = __shfl(out9[jj], g + 4 * cb + 16 * rg);

    // ---- 16 lanes store one full row each: 144 B contiguous, 9 x dwordx4
    if (jg == 0) {
        float* dst = Sh + (size_t)h * VV * JT + (size_t)(row0 + g) * JT;
#pragma unroll
        for (int q4 = 0; q4 < 9; ++q4)
            *(float4*)(dst + q4 * 4) = make_float4(out[4*q4], out[4*q4+1],
                                                   out[4*q4+2], out[4*q4+3]);
    }
}

// ---------------------------------------------------------------------------
// Pass B: per (batch, 256-token chunk): sum the 2 K-half planes of {s,u,v}
// per token (Sh = 9.2 MB, L2-hot), exp-sum -> one {L,d0,d1} partial.
// ---------------------------------------------------------------------------
__global__ __launch_bounds__(256) void gather_pass(
    const int* __restrict__ tokens, const float* __restrict__ Sh,
    float4* __restrict__ part)
{
    const int b     = blockIdx.x;
    const int chunk = blockIdx.y;
    const int tid   = threadIdx.x;

    const int tok = tokens[(size_t)b * SS + chunk * 256 + tid];
    const float* p0 = Sh + (size_t)tok * JT;
    const float* p1 = p0 + (size_t)VV * JT;

    const float s   = p0[b] + p1[b];                     // q_b . x_t
    const float2 a0 = *(const float2*)(p0 + 32);
    const float2 a1 = *(const float2*)(p1 + 32);
    const float u = a0.x + a1.x, v = a0.y + a1.y;        // w0.x_t, w1.x_t
    const float pe = __expf(s);                          // |s| <~ 0.5
    float L = pe, d0 = pe * u, d1 = pe * v;

#pragma unroll
    for (int off = 32; off > 0; off >>= 1) {
        L  += __shfl_xor(L,  off);
        d0 += __shfl_xor(d0, off);
        d1 += __shfl_xor(d1, off);
    }

    __shared__ float sL[4], s0[4], s1[4];
    const int wave = tid >> 6, lane = tid & 63;
    if (lane == 0) { sL[wave] = L; s0[wave] = d0; s1[wave] = d1; }
    __syncthreads();
    if (tid == 0) {
        part[(size_t)b * GCH + chunk] =
            make_float4(sL[0] + sL[1] + sL[2] + sL[3],
                        s0[0] + s0[1] + s0[2] + s0[3],
                        s1[0] + s1[1] + s1[2] + s1[3], 0.f);
    }
}

// ---------------------------------------------------------------------------
// Pass C: fold the 8 chunk-partials per batch; emit logits. One tiny block.
// ---------------------------------------------------------------------------
__global__ __launch_bounds__(256) void final_merge(
    const float4* __restrict__ part, const float* __restrict__ cls_b,
    float* __restrict__ out)
{
    const int tid = threadIdx.x;       // 256 = 32 b x 8 chunks
    const int b = tid >> 3, i = tid & 7;
    const float4 v = part[b * GCH + i];
    float L = v.x, d0 = v.y, d1 = v.z;
#pragma unroll
    for (int off = 4; off > 0; off >>= 1) {   // 8-lane groups, wave-aligned
        L  += __shfl_xor(L,  off);
        d0 += __shfl_xor(d0, off);
        d1 += __shfl_xor(d1, off);
    }
    if (i == 0) {
        const float inv = 1.0f / L;
        out[b * 2 + 0] = d0 * inv + cls_b[0];
        out[b * 2 + 1] = d1 * inv + cls_b[1];
    }
}

// ---------------------------------------------------------------------------
extern "C" void kernel_launch(void* const* d_in, const int* in_sizes, int n_in,
                              void* d_out, int out_size, void* d_ws, size_t ws_size,
                              hipStream_t stream)
{
    const int*   tokens = (const int*)  d_in[0];   // (32, 2048)
    const float* emb    = (const float*)d_in[1];   // (32000, 512)
    const float* cls_w  = (const float*)d_in[2];   // (2, 512)
    const float* cls_b  = (const float*)d_in[3];   // (2,)
    float*       out    = (float*)d_out;           // (32, 2)

    // Workspace:
    //   QT[36][512]          =  73.7 KB  (j-major)
    //   Sh[2][32000][36]     =   9.2 MB  (two K-half planes, written once)
    //   part[32][8] float4   =   2.0 KB
    float*  QT   = (float*)d_ws;
    float*  Sh   = QT + (size_t)JT * DD;
    float4* part = (float4*)(Sh + (size_t)2 * VV * JT);

    build_qt   <<<JT, 128, 0, stream>>>(tokens, emb, cls_w, QT);
    score_pass <<<dim3(VV / 64, 2), 256, 0, stream>>>(emb, QT, Sh);
    gather_pass<<<dim3(BB, GCH), 256, 0, stream>>>(tokens, Sh, part);
    final_merge<<<1, 256, 0, stream>>>(part, cls_b, out);
}

// Round 9
// 154.493 us; speedup vs baseline: 1.2708x; 1.2708x over previous
//
#include <hip/hip_runtime.h>
#include <math.h>

// Problem constants (B,S,D,V,C) = (32, 2048, 512, 32000, 2)
#define BB   32
#define SS   2048
#define DD   512
#define VV   32000
#define JT   36              // 32 q-rows + w0 + w1 + 2 zero rows
#define QRS4 289             // LDS region stride in float4 (288 + 1; 289 % 8 == 1)
#define GCH  8               // gather token-chunks per batch

// ---------------------------------------------------------------------------
// Pass 0: QTt[512][36] (d-major): QTt[d][j] = src_j[d]
//   j<32 : emb[tokens[j,0]] ; 32/33 : cls_w rows ; 34/35 : zero pad.
// (r4's measured-clean version.)
// ---------------------------------------------------------------------------
__global__ __launch_bounds__(256) void build_qt(
    const int* __restrict__ tokens, const float* __restrict__ emb,
    const float* __restrict__ cls_w, float* __restrict__ QTt)
{
    const int d = blockIdx.x * 256 + threadIdx.x;   // 0..511
    float v[JT];
#pragma unroll
    for (int j = 0; j < 32; ++j) {
        const int tok = tokens[(size_t)j * SS];     // block-uniform -> s_load
        v[j] = emb[(size_t)tok * DD + d];
    }
    v[32] = cls_w[d];
    v[33] = cls_w[DD + d];
    v[34] = 0.f; v[35] = 0.f;

    float* dst = QTt + (size_t)d * JT;
#pragma unroll
    for (int j = 0; j < JT; j += 4)
        *(float4*)(dst + j) = make_float4(v[j], v[j+1], v[j+2], v[j+3]);
}

// ---------------------------------------------------------------------------
// Pass A: Sh[h][v][j] = sum_{d in half h} emb[v][d] * QTt[d][j]
// r5's measured-clean skeleton (44us, 0 conflicts, FETCH 55MB, WRITE 4.5MB)
// with ONE structural change: K-split-2 via grid.y -> LDS panel 37KB ->
// 4 blocks/CU = 16 waves/CU (r5 had 2/CU; its limit was LDS issue + thin TLP).
//
// Lane (g = l&7: 32-dim subsegment, i = l>>3): rows {row0, row0+8}, acc 2x36.
// Per 4-dim chunk: 36 broadcast ds_read_b128 feed 288 FMAs.
// Banks (r5's verified invariant): region stride 289 f4 == 1 (mod 8); per
// instruction the 8 distinct addrs (one per g) hit all 8 bank-quads
// disjointly, 8-fold broadcast within each -> conflict-free.
// K folded in-wave: 3-step shfl_xor butterfly over the 8 g-lanes; g==0 lanes
// store full 144B contiguous rows (r5's clean write pattern).
// __launch_bounds__(256,2): the empirically no-spill setting (arg2=4 caps
// VGPR at 64 and caused r7/r8's scratch-traffic blowup).
// ---------------------------------------------------------------------------
__global__ __launch_bounds__(256, 2) void score_pass(
    const float* __restrict__ emb, const float* __restrict__ QTt,
    float* __restrict__ Sh)
{
    const int bx  = blockIdx.x;          // 0..499 row block (64 rows)
    const int h   = blockIdx.y;          // 0..1   K half (256 dims)
    const int tid = threadIdx.x;
    const int w   = tid >> 6;            // wave 0..3
    const int l   = tid & 63;
    const int g   = l & 7;               // 32-dim subsegment
    const int i   = l >> 3;              // row index (owns i, i+8)

    __shared__ float4 qs[8 * QRS4];      // 37.0 KB -> 4 blocks/CU

    // ---- stage QTt rows [h*256, h*256+256) -> 8 regions of 288 f4 (+1 pad)
    // source is contiguous d-major (row = 9 f4); 9 f4 per thread.
#pragma unroll
    for (int it = 0; it < 9; ++it) {
        const int t  = it * 256 + tid;          // flat f4 idx 0..2303
        const int gg = t / 288, r = t % 288;    // region / (d*9 + j4)
        qs[gg * QRS4 + r] = ((const float4*)QTt)[(h * 256 + gg * 32) * 9 + r];
    }
    __syncthreads();

    const int row0 = bx * 64 + w * 16 + i;               // rows row0, row0+8
    const float* x0 = emb + (size_t)row0 * DD + h * 256 + g * 32;
    const float* x1 = x0 + 8 * DD;

    float a0[JT], a1[JT];
#pragma unroll
    for (int k = 0; k < JT; ++k) { a0[k] = 0.f; a1[k] = 0.f; }

    float4 c0 = *(const float4*)x0;
    float4 c1 = *(const float4*)x1;

    for (int c = 0; c < 8; ++c) {                        // 8 chunks of 4 dims
        float4 n0, n1;
        if (c + 1 < 8) {
            n0 = *(const float4*)(x0 + (c + 1) * 4);
            n1 = *(const float4*)(x1 + (c + 1) * 4);
        }

        const float4* qbase = qs + g * QRS4 + c * 36;    // (c*4+dd)*9 = c*36+dd*9
#pragma unroll
        for (int dd = 0; dd < 4; ++dd) {
            const float4* qd = qbase + dd * 9;
            const float xs0 = (dd == 0) ? c0.x : (dd == 1) ? c0.y
                            : (dd == 2) ? c0.z : c0.w;
            const float xs1 = (dd == 0) ? c1.x : (dd == 1) ? c1.y
                            : (dd == 2) ? c1.z : c1.w;
#pragma unroll
            for (int jq = 0; jq < 9; ++jq) {
                const float4 q = qd[jq];                 // broadcast b128
                a0[4*jq+0] = fmaf(xs0, q.x, a0[4*jq+0]);
                a0[4*jq+1] = fmaf(xs0, q.y, a0[4*jq+1]);
                a0[4*jq+2] = fmaf(xs0, q.z, a0[4*jq+2]);
                a0[4*jq+3] = fmaf(xs0, q.w, a0[4*jq+3]);
                a1[4*jq+0] = fmaf(xs1, q.x, a1[4*jq+0]);
                a1[4*jq+1] = fmaf(xs1, q.y, a1[4*jq+1]);
                a1[4*jq+2] = fmaf(xs1, q.z, a1[4*jq+2]);
                a1[4*jq+3] = fmaf(xs1, q.w, a1[4*jq+3]);
            }
        }
        c0 = n0; c1 = n1;
    }

    // ---- in-wave K-reduction: butterfly over the 8 g-lanes (lane bits 0..2)
#pragma unroll
    for (int off = 1; off < 8; off <<= 1)
#pragma unroll
        for (int k = 0; k < JT; ++k) {
            a0[k] += __shfl_xor(a0[k], off);
            a1[k] += __shfl_xor(a1[k], off);
        }

    // ---- g==0 lanes (8/wave) store 2 full rows each: 144B contiguous bursts
    if (g == 0) {
        float* plane = Sh + (size_t)h * VV * JT;
        float* d0 = plane + (size_t)row0 * JT;
        float* d1 = plane + (size_t)(row0 + 8) * JT;
#pragma unroll
        for (int q4 = 0; q4 < 9; ++q4) {
            *(float4*)(d0 + q4 * 4) = make_float4(a0[4*q4], a0[4*q4+1],
                                                  a0[4*q4+2], a0[4*q4+3]);
            *(float4*)(d1 + q4 * 4) = make_float4(a1[4*q4], a1[4*q4+1],
                                                  a1[4*q4+2], a1[4*q4+3]);
        }
    }
}

// ---------------------------------------------------------------------------
// Pass B: per (batch, 256-token chunk): sum the 2 K-half planes of {s,u,v}
// per token (Sh = 9.2 MB, L2-hot), exp-sum -> one {L,d0,d1} partial.
// ---------------------------------------------------------------------------
__global__ __launch_bounds__(256) void gather_pass(
    const int* __restrict__ tokens, const float* __restrict__ Sh,
    float4* __restrict__ part)
{
    const int b     = blockIdx.x;
    const int chunk = blockIdx.y;
    const int tid   = threadIdx.x;

    const int tok = tokens[(size_t)b * SS + chunk * 256 + tid];
    const float* p0 = Sh + (size_t)tok * JT;
    const float* p1 = p0 + (size_t)VV * JT;

    const float s   = p0[b] + p1[b];                     // q_b . x_t
    const float2 a0 = *(const float2*)(p0 + 32);
    const float2 a1 = *(const float2*)(p1 + 32);
    const float u = a0.x + a1.x, v = a0.y + a1.y;        // w0.x_t, w1.x_t
    const float pe = __expf(s);                          // |s| <~ 0.5
    float L = pe, d0 = pe * u, d1 = pe * v;

#pragma unroll
    for (int off = 32; off > 0; off >>= 1) {
        L  += __shfl_xor(L,  off);
        d0 += __shfl_xor(d0, off);
        d1 += __shfl_xor(d1, off);
    }

    __shared__ float sL[4], s0[4], s1[4];
    const int wave = tid >> 6, lane = tid & 63;
    if (lane == 0) { sL[wave] = L; s0[wave] = d0; s1[wave] = d1; }
    __syncthreads();
    if (tid == 0) {
        part[(size_t)b * GCH + chunk] =
            make_float4(sL[0] + sL[1] + sL[2] + sL[3],
                        s0[0] + s0[1] + s0[2] + s0[3],
                        s1[0] + s1[1] + s1[2] + s1[3], 0.f);
    }
}

// ---------------------------------------------------------------------------
// Pass C: fold the 8 chunk-partials per batch; emit logits. One tiny block.
// ---------------------------------------------------------------------------
__global__ __launch_bounds__(256) void final_merge(
    const float4* __restrict__ part, const float* __restrict__ cls_b,
    float* __restrict__ out)
{
    const int tid = threadIdx.x;       // 256 = 32 b x 8 chunks
    const int b = tid >> 3, i = tid & 7;
    const float4 v = part[b * GCH + i];
    float L = v.x, d0 = v.y, d1 = v.z;
#pragma unroll
    for (int off = 4; off > 0; off >>= 1) {   // 8-lane groups, wave-aligned
        L  += __shfl_xor(L,  off);
        d0 += __shfl_xor(d0, off);
        d1 += __shfl_xor(d1, off);
    }
    if (i == 0) {
        const float inv = 1.0f / L;
        out[b * 2 + 0] = d0 * inv + cls_b[0];
        out[b * 2 + 1] = d1 * inv + cls_b[1];
    }
}

// ---------------------------------------------------------------------------
extern "C" void kernel_launch(void* const* d_in, const int* in_sizes, int n_in,
                              void* d_out, int out_size, void* d_ws, size_t ws_size,
                              hipStream_t stream)
{
    const int*   tokens = (const int*)  d_in[0];   // (32, 2048)
    const float* emb    = (const float*)d_in[1];   // (32000, 512)
    const float* cls_w  = (const float*)d_in[2];   // (2, 512)
    const float* cls_b  = (const float*)d_in[3];   // (2,)
    float*       out    = (float*)d_out;           // (32, 2)

    // Workspace:
    //   QTt[512][36]         =  73.7 KB  (d-major)
    //   Sh[2][32000][36]     =   9.2 MB  (two K-half planes, written once)
    //   part[32][8] float4   =   2.0 KB
    float*  QTt  = (float*)d_ws;
    float*  Sh   = QTt + (size_t)DD * JT;
    float4* part = (float4*)(Sh + (size_t)2 * VV * JT);

    build_qt   <<<2, 256, 0, stream>>>(tokens, emb, cls_w, QTt);
    score_pass <<<dim3(VV / 64, 2), 256, 0, stream>>>(emb, QTt, Sh);
    gather_pass<<<dim3(BB, GCH), 256, 0, stream>>>(tokens, Sh, part);
    final_merge<<<1, 256, 0, stream>>>(part, cls_b, out);
}